// Round 7
// baseline (8663.396 us; speedup 1.0000x reference)
//
#include <hip/hip_runtime.h>

#define NREL 8

// ---- per-(dst,rel) edge counts -> reciprocal (for mean) ----
__global__ void hist_k(const int* __restrict__ dst, const int* __restrict__ et,
                       int* __restrict__ cnt, int nE) {
  int i = blockIdx.x * blockDim.x + threadIdx.x;
  if (i < nE) atomicAdd(&cnt[dst[i] * NREL + et[i]], 1);
}

__global__ void inv_k(const int* __restrict__ cnt, float* __restrict__ inv, int n) {
  int i = blockIdx.x * blockDim.x + threadIdx.x;
  if (i < n) inv[i] = 1.0f / (float)(cnt[i] > 1 ? cnt[i] : 1);
}

// ---- relation histogram (LDS-aggregated: 8 global atomics per block) ----
__global__ void hist8_k(const int* __restrict__ et, int nE, int* __restrict__ rcnt) {
  __shared__ int lh[NREL];
  if (threadIdx.x < NREL) lh[threadIdx.x] = 0;
  __syncthreads();
  int i = blockIdx.x * blockDim.x + threadIdx.x;
  if (i < nE) atomicAdd(&lh[et[i]], 1);
  __syncthreads();
  if (threadIdx.x < NREL && lh[threadIdx.x]) atomicAdd(&rcnt[threadIdx.x], lh[threadIdx.x]);
}

__global__ void prefix_k(const int* __restrict__ rcnt, int* __restrict__ roff,
                         int* __restrict__ rcur) {
  roff[0] = 0;
  for (int r = 0; r < NREL; ++r) { roff[r + 1] = roff[r] + rcnt[r]; rcur[r] = roff[r]; }
}

// ---- bucket edge ids by relation (order within bucket arbitrary) ----
__global__ void fill_k(const int* __restrict__ et, int nE, int* __restrict__ rcur,
                       int* __restrict__ rlist) {
  __shared__ int lh[NREL], lbase[NREL];
  if (threadIdx.x < NREL) lh[threadIdx.x] = 0;
  __syncthreads();
  int i = blockIdx.x * blockDim.x + threadIdx.x;
  int t = 0, myoff = 0;
  if (i < nE) { t = et[i]; myoff = atomicAdd(&lh[t], 1); }
  __syncthreads();
  if (threadIdx.x < NREL && lh[threadIdx.x])
    lbase[threadIdx.x] = atomicAdd(&rcur[threadIdx.x], lh[threadIdx.x]);
  __syncthreads();
  if (i < nE) rlist[lbase[t] + myoff] = i;
}

// ---- persistent scatter for one relation: agg[dst] += x[src]*inv[dst*8+r] ----
template<int D>
__global__ void scatter_r_k(const float* __restrict__ xin, const int* __restrict__ src,
                            const int* __restrict__ dst, const int* __restrict__ rlist,
                            const int* __restrict__ roff, int r,
                            const float* __restrict__ inv, float* __restrict__ agg) {
  constexpr int V = D / 64;  // floats per lane
  const int base = roff[r];
  const int n = roff[r + 1] - base;
  const int* lst = rlist + base;
  const int lane = threadIdx.x & 63;
  const int wid = (blockIdx.x * blockDim.x + threadIdx.x) >> 6;
  const int nw = (gridDim.x * blockDim.x) >> 6;
  for (int i = wid; i < n; i += nw) {
    int e = lst[i];
    int s = src[e], d = dst[e];
    float w = inv[d * NREL + r];
    const float* xp = xin + (size_t)s * D + lane * V;
    float* mp = agg + (size_t)d * D + lane * V;
    if constexpr (V == 2) {
      float2 v = *(const float2*)xp;
      unsafeAtomicAdd(mp + 0, v.x * w);
      unsafeAtomicAdd(mp + 1, v.y * w);
    } else {
      float4 v = *(const float4*)xp;
      unsafeAtomicAdd(mp + 0, v.x * w);
      unsafeAtomicAdd(mp + 1, v.y * w);
      unsafeAtomicAdd(mp + 2, v.z * w);
      unsafeAtomicAdd(mp + 3, v.w * w);
    }
  }
}

// ---- fp32 GEMM: C (+)= A1@B1 [+ A2@B2] [+ bias], optional relu ----
// 128x128 tile, 256 threads, 8x8 register tile, KB=16 LDS chunk.
__global__ __launch_bounds__(256)
void gemm2_k(const float* __restrict__ A1, int K1, const float* __restrict__ B1,
             const float* __restrict__ A2, int K2, const float* __restrict__ B2,
             const float* __restrict__ bias, float* __restrict__ C,
             int loadC, int relu, int M, int O) {
  constexpr int BM = 128, BN = 128, KB = 16;
  __shared__ float As[KB][BM + 4];
  __shared__ float Bs[KB][BN + 4];
  const int tid = threadIdx.x;
  const int tx = tid & 15, ty = tid >> 4;
  const int m0 = blockIdx.x * BM;
  const int n0 = blockIdx.y * BN;

  float acc[8][8];
#pragma unroll
  for (int i = 0; i < 8; ++i)
#pragma unroll
    for (int j = 0; j < 8; ++j) acc[i][j] = 0.f;

  const int akc = (tid & 3) * 4;
  const int amr = tid >> 2;
  const int bnc = (tid & 31) * 4;
  const int bkr = tid >> 5;

  auto tile_loop = [&](const float* __restrict__ A, const float* __restrict__ B, int K) {
    for (int k0 = 0; k0 < K; k0 += KB) {
      __syncthreads();
#pragma unroll
      for (int p = 0; p < 2; ++p) {
        int ml = amr + p * 64;
        int m = m0 + ml;
        float4 v = make_float4(0.f, 0.f, 0.f, 0.f);
        if (m < M) v = *(const float4*)(A + (size_t)m * K + k0 + akc);
        As[akc + 0][ml] = v.x;
        As[akc + 1][ml] = v.y;
        As[akc + 2][ml] = v.z;
        As[akc + 3][ml] = v.w;
      }
#pragma unroll
      for (int p = 0; p < 2; ++p) {
        int k = bkr + p * 8;
        *(float4*)&Bs[k][bnc] = *(const float4*)(B + (size_t)(k0 + k) * O + n0 + bnc);
      }
      __syncthreads();
#pragma unroll
      for (int kk = 0; kk < KB; ++kk) {
        float a[8], b[8];
        *(float4*)&a[0] = *(const float4*)&As[kk][ty * 8];
        *(float4*)&a[4] = *(const float4*)&As[kk][ty * 8 + 4];
        *(float4*)&b[0] = *(const float4*)&Bs[kk][tx * 8];
        *(float4*)&b[4] = *(const float4*)&Bs[kk][tx * 8 + 4];
#pragma unroll
        for (int i = 0; i < 8; ++i)
#pragma unroll
          for (int j = 0; j < 8; ++j)
            acc[i][j] = fmaf(a[i], b[j], acc[i][j]);
      }
    }
  };
  tile_loop(A1, B1, K1);
  if (A2) tile_loop(A2, B2, K2);

  float bv[8];
#pragma unroll
  for (int j = 0; j < 8; ++j) bv[j] = bias ? bias[n0 + tx * 8 + j] : 0.f;
#pragma unroll
  for (int i = 0; i < 8; ++i) {
    int m = m0 + ty * 8 + i;
    if (m < M) {
      float* op = C + (size_t)m * O + n0 + tx * 8;
      float o[8];
      if (loadC) {
        float4 c0 = *(const float4*)(op);
        float4 c1 = *(const float4*)(op + 4);
        o[0] = c0.x; o[1] = c0.y; o[2] = c0.z; o[3] = c0.w;
        o[4] = c1.x; o[5] = c1.y; o[6] = c1.z; o[7] = c1.w;
      } else {
#pragma unroll
        for (int j = 0; j < 8; ++j) o[j] = 0.f;
      }
#pragma unroll
      for (int j = 0; j < 8; ++j) {
        o[j] += acc[i][j] + bv[j];
        if (relu) o[j] = fmaxf(o[j], 0.f);
      }
      *(float4*)(op) = *(float4*)&o[0];
      *(float4*)(op + 4) = *(float4*)&o[4];
    }
  }
}

extern "C" void kernel_launch(void* const* d_in, const int* in_sizes, int n_in,
                              void* d_out, int out_size, void* d_ws, size_t ws_size,
                              hipStream_t stream) {
  const float* x  = (const float*)d_in[0];
  const int* eidx = (const int*)d_in[1];
  const int* etyp = (const int*)d_in[2];
  const float* W1 = (const float*)d_in[3];
  const float* r1 = (const float*)d_in[4];
  const float* b1 = (const float*)d_in[5];
  const float* W2 = (const float*)d_in[6];
  const float* r2 = (const float*)d_in[7];
  const float* b2 = (const float*)d_in[8];
  const float* W3 = (const float*)d_in[9];
  const float* r3 = (const float*)d_in[10];
  const float* b3 = (const float*)d_in[11];
  float* out = (float*)d_out;

  const int N = in_sizes[0] / 128;  // 50000
  const int E = in_sizes[2];        // 800000
  const int* src = eidx;
  const int* dst = eidx + E;
  const int NSEG = N * NREL;
  (void)n_in; (void)out_size;

  // workspace carve (~160 MB)
  auto al = [](size_t v) { return (v + 255) & ~(size_t)255; };
  char* p = (char*)d_ws;
  int* cnt    = (int*)p;   p += al((size_t)NSEG * 4);
  float* inv  = (float*)p; p += al((size_t)NSEG * 4);
  int* rcnt   = (int*)p;   p += al(NREL * 4);
  int* roff   = (int*)p;   p += al((NREL + 1) * 4);
  int* rcur   = (int*)p;   p += al(NREL * 4);
  int* rlist  = (int*)p;   p += al((size_t)E * 4);
  float* agg  = (float*)p; p += al((size_t)N * 256 * 4);
  float* h1   = (float*)p; p += al((size_t)N * 256 * 4);
  float* h2   = (float*)p; p += al((size_t)N * 256 * 4);
  if ((size_t)(p - (char*)d_ws) > ws_size) return;  // diagnostic: fail clean, not SIGABRT

  // ---- graph structure (fixed across layers): counts, reciprocals, relation buckets
  hipMemsetAsync(cnt, 0, (size_t)NSEG * 4, stream);
  hipMemsetAsync(rcnt, 0, NREL * 4, stream);
  hist_k<<<(E + 255) / 256, 256, 0, stream>>>(dst, etyp, cnt, E);
  inv_k<<<(NSEG + 255) / 256, 256, 0, stream>>>(cnt, inv, NSEG);
  hist8_k<<<(E + 255) / 256, 256, 0, stream>>>(etyp, E, rcnt);
  prefix_k<<<1, 1, 0, stream>>>(rcnt, roff, rcur);
  fill_k<<<(E + 255) / 256, 256, 0, stream>>>(etyp, E, rcur, rlist);

  // ---- one layer: Y = relu?( sum_r agg_r@W[r] + xin@root + bias )
  auto layer = [&](const float* xin, int D, const float* W, const float* root,
                   const float* bias, float* Y, int O, bool relu) {
    for (int r = 0; r < NREL; ++r) {
      hipMemsetAsync(agg, 0, (size_t)N * D * 4, stream);
      if (D == 128)
        scatter_r_k<128><<<512, 256, 0, stream>>>(xin, src, dst, rlist, roff, r, inv, agg);
      else
        scatter_r_k<256><<<512, 256, 0, stream>>>(xin, src, dst, rlist, roff, r, inv, agg);
      dim3 g((N + 127) / 128, O / 128);
      gemm2_k<<<g, 256, 0, stream>>>(agg, D, W + (size_t)r * D * O,
                                     r == 0 ? xin : nullptr, D, r == 0 ? root : nullptr,
                                     r == 0 ? bias : nullptr, Y,
                                     /*loadC=*/r > 0, /*relu=*/(relu && r == NREL - 1) ? 1 : 0,
                                     N, O);
    }
  };

  layer(x,  128, W1, r1, b1, h1, 256, true);
  layer(h1, 256, W2, r2, b2, h2, 256, true);
  layer(h2, 256, W3, r3, b3, out, 128, false);
}

// Round 8
// 2724.344 us; speedup vs baseline: 3.1800x; 3.1800x over previous
//
#include <hip/hip_runtime.h>

#define NREL 8
#define SCHUNK 2048

// ---- per-(dst,rel) edge counts ----
__global__ void hist_k(const int* __restrict__ dst, const int* __restrict__ et,
                       int* __restrict__ cnt, int nE) {
  int i = blockIdx.x * blockDim.x + threadIdx.x;
  if (i < nE) atomicAdd(&cnt[dst[i] * NREL + et[i]], 1);
}

// ---- 3-pass exclusive scan over cnt[n] -> off[n+1] (and init cur=off) ----
__global__ void scan1_k(const int* __restrict__ cnt, int n,
                        int* __restrict__ thexc, int* __restrict__ bsum) {
  __shared__ int sh[256];
  int b = blockIdx.x, t = threadIdx.x;
  int base = b * SCHUNK + t * 8;
  int s = 0;
#pragma unroll
  for (int j = 0; j < 8; ++j) { int idx = base + j; s += (idx < n) ? cnt[idx] : 0; }
  sh[t] = s;
  __syncthreads();
  for (int d = 1; d < 256; d <<= 1) {           // inclusive Hillis-Steele
    int v = (t >= d) ? sh[t - d] : 0;
    __syncthreads();
    sh[t] += v;
    __syncthreads();
  }
  thexc[b * 256 + t] = sh[t] - s;               // exclusive within block
  if (t == 255) bsum[b] = sh[255];
}

__global__ void scan2_k(int* __restrict__ bsum, int nb, int total,
                        int* __restrict__ off, int n) {
  int run = 0;
  for (int i = 0; i < nb; ++i) { int v = bsum[i]; bsum[i] = run; run += v; }
  off[n] = total;
}

__global__ void scan3_k(const int* __restrict__ cnt, int n, const int* __restrict__ thexc,
                        const int* __restrict__ bsum, int* __restrict__ off,
                        int* __restrict__ cur) {
  int b = blockIdx.x, t = threadIdx.x;
  int base = b * SCHUNK + t * 8;
  int run = bsum[b] + thexc[b * 256 + t];
#pragma unroll
  for (int j = 0; j < 8; ++j) {
    int idx = base + j;
    if (idx < n) { int c = cnt[idx]; off[idx] = run; cur[idx] = run; run += c; }  // cur may alias cnt
  }
}

// ---- counting-sort src ids by segment (dst*8+rel) ----
__global__ void fill2_k(const int* __restrict__ src, const int* __restrict__ dst,
                        const int* __restrict__ et, int nE,
                        int* __restrict__ cur, int* __restrict__ slist) {
  int i = blockIdx.x * blockDim.x + threadIdx.x;
  if (i < nE) {
    int seg = dst[i] * NREL + et[i];
    int p = atomicAdd(&cur[seg], 1);
    slist[p] = src[i];
  }
}

// ---- dst-parallel gather-mean for one relation: agg[d] = mean_{e in (d,r)} x[src_e] ----
template<int D>
__global__ void gather_r_k(const float* __restrict__ xin, const int* __restrict__ slist,
                           const int* __restrict__ off, int r, float* __restrict__ agg, int N) {
  constexpr int V = D / 64;  // floats per lane
  int lane = threadIdx.x & 63;
  int d = (blockIdx.x * blockDim.x + threadIdx.x) >> 6;  // one wave per dst row
  if (d >= N) return;
  int a = off[d * NREL + r], b = off[d * NREL + r + 1];
  float s[V];
#pragma unroll
  for (int j = 0; j < V; ++j) s[j] = 0.f;
  for (int i = a; i < b; ++i) {
    const float* xp = xin + (size_t)slist[i] * D + lane * V;
    if constexpr (V == 2) {
      float2 v = *(const float2*)xp;
      s[0] += v.x; s[1] += v.y;
    } else {
      float4 v = *(const float4*)xp;
      s[0] += v.x; s[1] += v.y; s[2] += v.z; s[3] += v.w;
    }
  }
  float w = 1.0f / (float)((b - a) > 1 ? (b - a) : 1);
  float* mp = agg + (size_t)d * D + lane * V;
  if constexpr (V == 2) {
    *(float2*)mp = make_float2(s[0] * w, s[1] * w);
  } else {
    *(float4*)mp = make_float4(s[0] * w, s[1] * w, s[2] * w, s[3] * w);
  }
}

// ---- fp32 GEMM: C (+)= A1@B1 [+ A2@B2] [+ bias], optional relu ----
__global__ __launch_bounds__(256)
void gemm2_k(const float* __restrict__ A1, int K1, const float* __restrict__ B1,
             const float* __restrict__ A2, int K2, const float* __restrict__ B2,
             const float* __restrict__ bias, float* __restrict__ C,
             int loadC, int relu, int M, int O) {
  constexpr int BM = 128, BN = 128, KB = 16;
  __shared__ float As[KB][BM + 4];
  __shared__ float Bs[KB][BN + 4];
  const int tid = threadIdx.x;
  const int tx = tid & 15, ty = tid >> 4;
  const int m0 = blockIdx.x * BM;
  const int n0 = blockIdx.y * BN;

  float acc[8][8];
#pragma unroll
  for (int i = 0; i < 8; ++i)
#pragma unroll
    for (int j = 0; j < 8; ++j) acc[i][j] = 0.f;

  const int akc = (tid & 3) * 4;
  const int amr = tid >> 2;
  const int bnc = (tid & 31) * 4;
  const int bkr = tid >> 5;

  auto tile_loop = [&](const float* __restrict__ A, const float* __restrict__ B, int K) {
    for (int k0 = 0; k0 < K; k0 += KB) {
      __syncthreads();
#pragma unroll
      for (int p = 0; p < 2; ++p) {
        int ml = amr + p * 64;
        int m = m0 + ml;
        float4 v = make_float4(0.f, 0.f, 0.f, 0.f);
        if (m < M) v = *(const float4*)(A + (size_t)m * K + k0 + akc);
        As[akc + 0][ml] = v.x;
        As[akc + 1][ml] = v.y;
        As[akc + 2][ml] = v.z;
        As[akc + 3][ml] = v.w;
      }
#pragma unroll
      for (int p = 0; p < 2; ++p) {
        int k = bkr + p * 8;
        *(float4*)&Bs[k][bnc] = *(const float4*)(B + (size_t)(k0 + k) * O + n0 + bnc);
      }
      __syncthreads();
#pragma unroll
      for (int kk = 0; kk < KB; ++kk) {
        float a[8], b[8];
        *(float4*)&a[0] = *(const float4*)&As[kk][ty * 8];
        *(float4*)&a[4] = *(const float4*)&As[kk][ty * 8 + 4];
        *(float4*)&b[0] = *(const float4*)&Bs[kk][tx * 8];
        *(float4*)&b[4] = *(const float4*)&Bs[kk][tx * 8 + 4];
#pragma unroll
        for (int i = 0; i < 8; ++i)
#pragma unroll
          for (int j = 0; j < 8; ++j)
            acc[i][j] = fmaf(a[i], b[j], acc[i][j]);
      }
    }
  };
  tile_loop(A1, B1, K1);
  if (A2) tile_loop(A2, B2, K2);

  float bv[8];
#pragma unroll
  for (int j = 0; j < 8; ++j) bv[j] = bias ? bias[n0 + tx * 8 + j] : 0.f;
#pragma unroll
  for (int i = 0; i < 8; ++i) {
    int m = m0 + ty * 8 + i;
    if (m < M) {
      float* op = C + (size_t)m * O + n0 + tx * 8;
      float o[8];
      if (loadC) {
        float4 c0 = *(const float4*)(op);
        float4 c1 = *(const float4*)(op + 4);
        o[0] = c0.x; o[1] = c0.y; o[2] = c0.z; o[3] = c0.w;
        o[4] = c1.x; o[5] = c1.y; o[6] = c1.z; o[7] = c1.w;
      } else {
#pragma unroll
        for (int j = 0; j < 8; ++j) o[j] = 0.f;
      }
#pragma unroll
      for (int j = 0; j < 8; ++j) {
        o[j] += acc[i][j] + bv[j];
        if (relu) o[j] = fmaxf(o[j], 0.f);
      }
      *(float4*)(op) = *(float4*)&o[0];
      *(float4*)(op + 4) = *(float4*)&o[4];
    }
  }
}

extern "C" void kernel_launch(void* const* d_in, const int* in_sizes, int n_in,
                              void* d_out, int out_size, void* d_ws, size_t ws_size,
                              hipStream_t stream) {
  const float* x  = (const float*)d_in[0];
  const int* eidx = (const int*)d_in[1];
  const int* etyp = (const int*)d_in[2];
  const float* W1 = (const float*)d_in[3];
  const float* r1 = (const float*)d_in[4];
  const float* b1 = (const float*)d_in[5];
  const float* W2 = (const float*)d_in[6];
  const float* r2 = (const float*)d_in[7];
  const float* b2 = (const float*)d_in[8];
  const float* W3 = (const float*)d_in[9];
  const float* r3 = (const float*)d_in[10];
  const float* b3 = (const float*)d_in[11];
  float* out = (float*)d_out;

  const int N = in_sizes[0] / 128;  // 50000
  const int E = in_sizes[2];        // 800000
  const int* src = eidx;
  const int* dst = eidx + E;
  const int NSEG = N * NREL;
  const int NB = (NSEG + SCHUNK - 1) / SCHUNK;
  (void)n_in; (void)out_size;

  // workspace carve (~160 MB, same footprint class as the passing round)
  auto al = [](size_t v) { return (v + 255) & ~(size_t)255; };
  char* p = (char*)d_ws;
  int* cnt    = (int*)p;   p += al((size_t)NSEG * 4);        // counts, later reused as 'cur'
  int* off    = (int*)p;   p += al((size_t)(NSEG + 1) * 4);
  int* thexc  = (int*)p;   p += al((size_t)NB * 256 * 4);
  int* bsum   = (int*)p;   p += al((size_t)NB * 4);
  int* slist  = (int*)p;   p += al((size_t)E * 4);           // src ids sorted by (dst,rel)
  float* agg  = (float*)p; p += al((size_t)N * 256 * 4);
  float* h1   = (float*)p; p += al((size_t)N * 256 * 4);
  float* h2   = (float*)p; p += al((size_t)N * 256 * 4);
  if ((size_t)(p - (char*)d_ws) > ws_size) return;  // fail clean, not SIGABRT

  // ---- build (dst,rel) CSR once (graph fixed across layers) ----
  hipMemsetAsync(cnt, 0, (size_t)NSEG * 4, stream);
  hist_k<<<(E + 255) / 256, 256, 0, stream>>>(dst, etyp, cnt, E);
  scan1_k<<<NB, 256, 0, stream>>>(cnt, NSEG, thexc, bsum);
  scan2_k<<<1, 1, 0, stream>>>(bsum, NB, E, off, NSEG);
  scan3_k<<<NB, 256, 0, stream>>>(cnt, NSEG, thexc, bsum, off, cnt /*cur aliases cnt*/);
  fill2_k<<<(E + 255) / 256, 256, 0, stream>>>(src, dst, etyp, E, cnt, slist);

  // ---- one layer: Y = relu?( sum_r mean_r@W[r] + xin@root + bias ) ----
  auto layer = [&](const float* xin, int D, const float* W, const float* root,
                   const float* bias, float* Y, int O, bool relu) {
    int gblocks = (N * 64 + 255) / 256;   // one wave per dst row
    for (int r = 0; r < NREL; ++r) {
      if (D == 128)
        gather_r_k<128><<<gblocks, 256, 0, stream>>>(xin, slist, off, r, agg, N);
      else
        gather_r_k<256><<<gblocks, 256, 0, stream>>>(xin, slist, off, r, agg, N);
      dim3 g((N + 127) / 128, O / 128);
      gemm2_k<<<g, 256, 0, stream>>>(agg, D, W + (size_t)r * D * O,
                                     r == 0 ? xin : nullptr, D, r == 0 ? root : nullptr,
                                     r == 0 ? bias : nullptr, Y,
                                     /*loadC=*/r > 0, /*relu=*/(relu && r == NREL - 1) ? 1 : 0,
                                     N, O);
    }
  };

  layer(x,  128, W1, r1, b1, h1, 256, true);
  layer(h1, 256, W2, r2, b2, h2, 256, true);
  layer(h2, 256, W3, r3, b3, out, 128, false);
}

// Round 12
// 1227.763 us; speedup vs baseline: 7.0562x; 2.2190x over previous
//
#include <hip/hip_runtime.h>

#define NREL 8
#define SCHUNK 2048

typedef __attribute__((ext_vector_type(8))) short bf16x8;
typedef __attribute__((ext_vector_type(4))) float f32x4;

__device__ __forceinline__ float bf2f(ushort u) {
  union { unsigned u; float f; } c; c.u = ((unsigned)u) << 16; return c.f;
}
__device__ __forceinline__ ushort f2bf(float f) {
  union { float f; unsigned u; } c; c.f = f;
  unsigned r = c.u + 0x7FFFu + ((c.u >> 16) & 1u);   // round-to-nearest-even
  return (ushort)(r >> 16);
}

// ======================= CSR build =======================
__global__ void hist_k(const int* __restrict__ dst, const int* __restrict__ et,
                       int* __restrict__ cnt, int nE) {
  int i = blockIdx.x * blockDim.x + threadIdx.x;
  if (i < nE) atomicAdd(&cnt[dst[i] * NREL + et[i]], 1);
}

__global__ void scan1_k(const int* __restrict__ cnt, int n,
                        int* __restrict__ thexc, int* __restrict__ bsum) {
  __shared__ int sh[256];
  int b = blockIdx.x, t = threadIdx.x;
  int base = b * SCHUNK + t * 8;
  int s = 0;
#pragma unroll
  for (int j = 0; j < 8; ++j) { int idx = base + j; s += (idx < n) ? cnt[idx] : 0; }
  sh[t] = s;
  __syncthreads();
  for (int d = 1; d < 256; d <<= 1) {
    int v = (t >= d) ? sh[t - d] : 0;
    __syncthreads();
    sh[t] += v;
    __syncthreads();
  }
  thexc[b * 256 + t] = sh[t] - s;
  if (t == 255) bsum[b] = sh[255];
}

__global__ void scan2_k(int* __restrict__ bsum, int nb, int total,
                        int* __restrict__ off, int n) {
  int run = 0;
  for (int i = 0; i < nb; ++i) { int v = bsum[i]; bsum[i] = run; run += v; }
  off[n] = total;
}

__global__ void scan3_k(const int* __restrict__ cnt, int n, const int* __restrict__ thexc,
                        const int* __restrict__ bsum, int* __restrict__ off,
                        int* __restrict__ cur) {
  int b = blockIdx.x, t = threadIdx.x;
  int base = b * SCHUNK + t * 8;
  int run = bsum[b] + thexc[b * 256 + t];
#pragma unroll
  for (int j = 0; j < 8; ++j) {
    int idx = base + j;
    if (idx < n) { int c = cnt[idx]; off[idx] = run; cur[idx] = run; run += c; }
  }
}

__global__ void fill2_k(const int* __restrict__ src, const int* __restrict__ dst,
                        const int* __restrict__ et, int nE,
                        int* __restrict__ cur, int* __restrict__ slist) {
  int i = blockIdx.x * blockDim.x + threadIdx.x;
  if (i < nE) {
    int seg = dst[i] * NREL + et[i];
    int p = atomicAdd(&cur[seg], 1);
    slist[p] = src[i];
  }
}

// ======================= conversions =======================
__global__ void f2b_k(const float* __restrict__ in, ushort* __restrict__ out, int n4) {
  int i = blockIdx.x * blockDim.x + threadIdx.x;
  if (i < n4) {
    float4 v = *(const float4*)(in + (size_t)i * 4);
    ushort4 o;
    o.x = f2bf(v.x); o.y = f2bf(v.y); o.z = f2bf(v.z); o.w = f2bf(v.w);
    *(ushort4*)(out + (size_t)i * 4) = o;
  }
}

// W[r][d][o] fp32 -> Wt[(r/G)][o][(r%G)*K + d] bf16
__global__ void wt_k(const float* __restrict__ W, ushort* __restrict__ Wt,
                     int R, int K, int O, int G) {
  size_t i = (size_t)blockIdx.x * blockDim.x + threadIdx.x;
  size_t tot = (size_t)R * K * O;
  if (i >= tot) return;
  int o = (int)(i % O);
  size_t t = i / O;
  int d = (int)(t % K);
  int r = (int)(t / K);
  Wt[((size_t)(r / G) * O + o) * ((size_t)G * K) + (size_t)(r % G) * K + d] = f2bf(W[i]);
}

// ===== gather NR relations (contiguous in slist) per dst row, bf16 in/out =====
template<int D, int NR>
__global__ void gatherN_k(const ushort* __restrict__ xb, const int* __restrict__ slist,
                          const int* __restrict__ off, int r0,
                          ushort* __restrict__ agg, int N) {
  constexpr int V = D / 64;
  int lane = threadIdx.x & 63;
  int d = (blockIdx.x * blockDim.x + threadIdx.x) >> 6;
  if (d >= N) return;
  int o[NR + 1];
#pragma unroll
  for (int j = 0; j <= NR; ++j) o[j] = off[d * NREL + r0 + j];
  const int bc = lane * V;
#pragma unroll
  for (int r = 0; r < NR; ++r) {
    float s[V];
#pragma unroll
    for (int j = 0; j < V; ++j) s[j] = 0.f;
    for (int i = o[r]; i < o[r + 1]; ++i) {
      const ushort* xp = xb + (size_t)slist[i] * D + bc;
      if constexpr (V == 2) {
        uint v = *(const uint*)xp;
        s[0] += bf2f((ushort)(v & 0xffff));
        s[1] += bf2f((ushort)(v >> 16));
      } else {
        ushort4 v = *(const ushort4*)xp;
        s[0] += bf2f(v.x); s[1] += bf2f(v.y); s[2] += bf2f(v.z); s[3] += bf2f(v.w);
      }
    }
    int c = o[r + 1] - o[r];
    float w = 1.f / (float)(c > 1 ? c : 1);
    ushort* mp = agg + (size_t)d * (NR * D) + r * D + bc;
    if constexpr (V == 2) {
      ushort2 st; st.x = f2bf(s[0] * w); st.y = f2bf(s[1] * w);
      *(ushort2*)mp = st;
    } else {
      ushort4 st; st.x = f2bf(s[0] * w); st.y = f2bf(s[1] * w);
      st.z = f2bf(s[2] * w); st.w = f2bf(s[3] * w);
      *(ushort4*)mp = st;
    }
  }
}

// ======================= bf16 MFMA GEMM (single A/B pair) =======================
// C (+)= A[M,K]@Bt^T [+bias][relu].  Bt is [O][K] row-major.
// 128x128 tile, 4 waves (2x2), wave = 64x64 via 4x4 frags of 16x16x32. BK=64, XOR-swizzled LDS.
template<bool CF32>
__global__ __launch_bounds__(256)
void mgemm_k(const ushort* __restrict__ A, int K, const ushort* __restrict__ Bt,
             const float* __restrict__ bias, void* __restrict__ Cv,
             int loadC, int relu, int M, int O) {
  __shared__ ushort Al[128 * 64];
  __shared__ ushort Bl[128 * 64];
  const int tid = threadIdx.x;
  const int lane = tid & 63;
  const int w = tid >> 6;
  const int wr = (w >> 1) * 64;
  const int wc = (w & 1) * 64;
  const int m0 = blockIdx.x * 128;
  const int n0 = blockIdx.y * 128;

  f32x4 acc[4][4];
#pragma unroll
  for (int i = 0; i < 4; ++i)
#pragma unroll
    for (int j = 0; j < 4; ++j) acc[i][j] = (f32x4){0.f, 0.f, 0.f, 0.f};

  const int srow = tid >> 3;   // 0..31
  const int schk = tid & 7;    // 0..7 (16B chunk within 128B row)

  for (int k0 = 0; k0 < K; k0 += 64) {
    __syncthreads();
#pragma unroll
    for (int p = 0; p < 4; ++p) {
      int row = p * 32 + srow;
      int gm = m0 + row;
      uint4 v = make_uint4(0, 0, 0, 0);
      if (gm < M) v = *(const uint4*)(A + (size_t)gm * K + k0 + schk * 8);
      *(uint4*)&Al[row * 64 + ((schk ^ (row & 7)) * 8)] = v;
    }
#pragma unroll
    for (int p = 0; p < 4; ++p) {
      int row = p * 32 + srow;
      uint4 v = *(const uint4*)(Bt + (size_t)(n0 + row) * K + k0 + schk * 8);
      *(uint4*)&Bl[row * 64 + ((schk ^ (row & 7)) * 8)] = v;
    }
    __syncthreads();
#pragma unroll
    for (int kk = 0; kk < 2; ++kk) {
      bf16x8 a_f[4], b_f[4];
      int slot = kk * 4 + (lane >> 4);
#pragma unroll
      for (int f = 0; f < 4; ++f) {
        int mr = wr + f * 16 + (lane & 15);
        a_f[f] = *(const bf16x8*)&Al[mr * 64 + ((slot ^ (mr & 7)) * 8)];
        int nc = wc + f * 16 + (lane & 15);
        b_f[f] = *(const bf16x8*)&Bl[nc * 64 + ((slot ^ (nc & 7)) * 8)];
      }
#pragma unroll
      for (int i = 0; i < 4; ++i)
#pragma unroll
        for (int j = 0; j < 4; ++j)
          acc[i][j] = __builtin_amdgcn_mfma_f32_16x16x32_bf16(a_f[i], b_f[j], acc[i][j], 0, 0, 0);
    }
  }

  float bv[4];
#pragma unroll
  for (int j = 0; j < 4; ++j) bv[j] = bias ? bias[n0 + wc + j * 16 + (lane & 15)] : 0.f;
#pragma unroll
  for (int i = 0; i < 4; ++i) {
#pragma unroll
    for (int rg = 0; rg < 4; ++rg) {
      int row = m0 + wr + i * 16 + (lane >> 4) * 4 + rg;
      if (row < M) {
#pragma unroll
        for (int j = 0; j < 4; ++j) {
          int col = n0 + wc + j * 16 + (lane & 15);
          float v = acc[i][j][rg] + bv[j];
          if (CF32) {
            float* C = (float*)Cv + (size_t)row * O + col;
            if (loadC) v += *C;
            if (relu) v = fmaxf(v, 0.f);
            *C = v;
          } else {
            ushort* C = (ushort*)Cv + (size_t)row * O + col;
            if (loadC) v += bf2f(*C);
            if (relu) v = fmaxf(v, 0.f);
            *C = f2bf(v);
          }
        }
      }
    }
  }
}

extern "C" void kernel_launch(void* const* d_in, const int* in_sizes, int n_in,
                              void* d_out, int out_size, void* d_ws, size_t ws_size,
                              hipStream_t stream) {
  const float* x  = (const float*)d_in[0];
  const int* eidx = (const int*)d_in[1];
  const int* etyp = (const int*)d_in[2];
  const float* W1 = (const float*)d_in[3];
  const float* r1 = (const float*)d_in[4];
  const float* b1 = (const float*)d_in[5];
  const float* W2 = (const float*)d_in[6];
  const float* r2 = (const float*)d_in[7];
  const float* b2 = (const float*)d_in[8];
  const float* W3 = (const float*)d_in[9];
  const float* r3 = (const float*)d_in[10];
  const float* b3 = (const float*)d_in[11];
  float* out = (float*)d_out;

  const int N = in_sizes[0] / 128;  // 50000
  const int E = in_sizes[2];        // 800000
  const int* src = eidx;
  const int* dst = eidx + E;
  const int NSEG = N * NREL;
  const int NB = (NSEG + SCHUNK - 1) / SCHUNK;
  (void)n_in; (void)out_size;

  // workspace carve (~118 MiB)
  auto al = [](size_t v) { return (v + 255) & ~(size_t)255; };
  char* p = (char*)d_ws;
  int* cnt    = (int*)p;    p += al((size_t)NSEG * 4);
  int* off    = (int*)p;    p += al((size_t)(NSEG + 1) * 4);
  int* thexc  = (int*)p;    p += al((size_t)NB * 256 * 4);
  int* bsum   = (int*)p;    p += al((size_t)NB * 4);
  int* slist  = (int*)p;    p += al((size_t)E * 4);
  ushort* xb  = (ushort*)p; p += al((size_t)N * 128 * 2);
  ushort* h1  = (ushort*)p; p += al((size_t)N * 256 * 2);
  ushort* h2  = (ushort*)p; p += al((size_t)N * 256 * 2);
  ushort* agg = (ushort*)p; p += al((size_t)N * 512 * 2);
  ushort* wt1 = (ushort*)p; p += al((size_t)NREL * 128 * 256 * 2);
  ushort* rt1 = (ushort*)p; p += al((size_t)128 * 256 * 2);
  ushort* wt2 = (ushort*)p; p += al((size_t)NREL * 256 * 256 * 2);
  ushort* rt2 = (ushort*)p; p += al((size_t)256 * 256 * 2);
  ushort* wt3 = (ushort*)p; p += al((size_t)NREL * 256 * 128 * 2);
  ushort* rt3 = (ushort*)p; p += al((size_t)256 * 128 * 2);
  size_t used = (size_t)(p - (char*)d_ws);
  if (used > ws_size) return;  // fail clean, not SIGABRT

  // DIAGNOSTIC INSURANCE: zero entire used workspace so every call (first or
  // poisoned-replay) sees identical initial state. ~20 us.
  hipMemsetAsync(d_ws, 0, used, stream);

  // ---- CSR over (dst,rel), built once per call ----
  hist_k<<<(E + 255) / 256, 256, 0, stream>>>(dst, etyp, cnt, E);
  scan1_k<<<NB, 256, 0, stream>>>(cnt, NSEG, thexc, bsum);
  scan2_k<<<1, 1, 0, stream>>>(bsum, NB, E, off, NSEG);
  scan3_k<<<NB, 256, 0, stream>>>(cnt, NSEG, thexc, bsum, off, cnt);
  fill2_k<<<(E + 255) / 256, 256, 0, stream>>>(src, dst, etyp, E, cnt, slist);

  // ---- conversions ----
  f2b_k<<<(N * 128 / 4 + 255) / 256, 256, 0, stream>>>(x, xb, N * 128 / 4);
  auto wconv = [&](const float* W, ushort* Wt, int R, int K, int O, int G) {
    size_t tot = (size_t)R * K * O;
    wt_k<<<(int)((tot + 255) / 256), 256, 0, stream>>>(W, Wt, R, K, O, G);
  };
  wconv(W1, wt1, NREL, 128, 256, 4);
  wconv(r1, rt1, 1, 128, 256, 1);
  wconv(W2, wt2, NREL, 256, 256, 2);
  wconv(r2, rt2, 1, 256, 256, 1);
  wconv(W3, wt3, NREL, 256, 128, 2);
  wconv(r3, rt3, 1, 256, 128, 1);

  const int gblocks = (N * 64 + 255) / 256;

  // ---- one layer: root pass writes C(+bias); NP relation passes RMW; relu on last ----
  auto layer = [&](const ushort* xin, int D, int NP, const ushort* Wt, const ushort* Rt,
                   const float* bias, void* Y, int O, bool relu, bool cf32) {
    dim3 g((N + 127) / 128, O / 128);
    if (cf32)
      mgemm_k<true><<<g, 256, 0, stream>>>(xin, D, Rt, bias, Y, 0, 0, N, O);
    else
      mgemm_k<false><<<g, 256, 0, stream>>>(xin, D, Rt, bias, Y, 0, 0, N, O);
    int NR = NREL / NP;
    for (int pass = 0; pass < NP; ++pass) {
      if (D == 128)
        gatherN_k<128, 4><<<gblocks, 256, 0, stream>>>(xin, slist, off, pass * 4, agg, N);
      else
        gatherN_k<256, 2><<<gblocks, 256, 0, stream>>>(xin, slist, off, pass * 2, agg, N);
      const ushort* Bt = Wt + (size_t)pass * O * (NR * D);
      int rl = (relu && pass == NP - 1) ? 1 : 0;
      if (cf32)
        mgemm_k<true><<<g, 256, 0, stream>>>(agg, NR * D, Bt, nullptr, Y, 1, rl, N, O);
      else
        mgemm_k<false><<<g, 256, 0, stream>>>(agg, NR * D, Bt, nullptr, Y, 1, rl, N, O);
    }
  };

  layer(xb, 128, 2, wt1, rt1, b1, h1, 256, true,  false);
  layer(h1, 256, 4, wt2, rt2, b2, h2, 256, true,  false);
  layer(h2, 256, 4, wt3, rt3, b3, out, 128, false, true);
}

// Round 13
// 1185.577 us; speedup vs baseline: 7.3073x; 1.0356x over previous
//
#include <hip/hip_runtime.h>

#define NREL 8
#define SCHUNK 2048

typedef __attribute__((ext_vector_type(8))) short bf16x8;
typedef __attribute__((ext_vector_type(4))) float f32x4;

__device__ __forceinline__ float bf2f(ushort u) {
  union { unsigned u; float f; } c; c.u = ((unsigned)u) << 16; return c.f;
}
__device__ __forceinline__ ushort f2bf(float f) {
  union { float f; unsigned u; } c; c.f = f;
  unsigned r = c.u + 0x7FFFu + ((c.u >> 16) & 1u);   // round-to-nearest-even
  return (ushort)(r >> 16);
}

// ======================= CSR build =======================
__global__ void hist_k(const int* __restrict__ dst, const int* __restrict__ et,
                       int* __restrict__ cnt, int nE) {
  int i = blockIdx.x * blockDim.x + threadIdx.x;
  if (i < nE) atomicAdd(&cnt[dst[i] * NREL + et[i]], 1);
}

__global__ void scan1_k(const int* __restrict__ cnt, int n,
                        int* __restrict__ thexc, int* __restrict__ bsum) {
  __shared__ int sh[256];
  int b = blockIdx.x, t = threadIdx.x;
  int base = b * SCHUNK + t * 8;
  int s = 0;
#pragma unroll
  for (int j = 0; j < 8; ++j) { int idx = base + j; s += (idx < n) ? cnt[idx] : 0; }
  sh[t] = s;
  __syncthreads();
  for (int d = 1; d < 256; d <<= 1) {
    int v = (t >= d) ? sh[t - d] : 0;
    __syncthreads();
    sh[t] += v;
    __syncthreads();
  }
  thexc[b * 256 + t] = sh[t] - s;
  if (t == 255) bsum[b] = sh[255];
}

__global__ void scan2_k(int* __restrict__ bsum, int nb, int total,
                        int* __restrict__ off, int n) {
  int run = 0;
  for (int i = 0; i < nb; ++i) { int v = bsum[i]; bsum[i] = run; run += v; }
  off[n] = total;
}

__global__ void scan3_k(const int* __restrict__ cnt, int n, const int* __restrict__ thexc,
                        const int* __restrict__ bsum, int* __restrict__ off,
                        int* __restrict__ cur) {
  int b = blockIdx.x, t = threadIdx.x;
  int base = b * SCHUNK + t * 8;
  int run = bsum[b] + thexc[b * 256 + t];
#pragma unroll
  for (int j = 0; j < 8; ++j) {
    int idx = base + j;
    if (idx < n) { int c = cnt[idx]; off[idx] = run; cur[idx] = run; run += c; }
  }
}

__global__ void fill2_k(const int* __restrict__ src, const int* __restrict__ dst,
                        const int* __restrict__ et, int nE,
                        int* __restrict__ cur, int* __restrict__ slist) {
  int i = blockIdx.x * blockDim.x + threadIdx.x;
  if (i < nE) {
    int seg = dst[i] * NREL + et[i];
    int p = atomicAdd(&cur[seg], 1);
    slist[p] = src[i];
  }
}

// ======================= conversions =======================
__global__ void f2b_k(const float* __restrict__ in, ushort* __restrict__ out, int n4) {
  int i = blockIdx.x * blockDim.x + threadIdx.x;
  if (i < n4) {
    float4 v = *(const float4*)(in + (size_t)i * 4);
    ushort4 o;
    o.x = f2bf(v.x); o.y = f2bf(v.y); o.z = f2bf(v.z); o.w = f2bf(v.w);
    *(ushort4*)(out + (size_t)i * 4) = o;
  }
}

// W[r][d][o] fp32 -> Wt[(r/G)][o][(r%G)*K + d] bf16
__global__ void wt_k(const float* __restrict__ W, ushort* __restrict__ Wt,
                     int R, int K, int O, int G) {
  size_t i = (size_t)blockIdx.x * blockDim.x + threadIdx.x;
  size_t tot = (size_t)R * K * O;
  if (i >= tot) return;
  int o = (int)(i % O);
  size_t t = i / O;
  int d = (int)(t % K);
  int r = (int)(t / K);
  Wt[((size_t)(r / G) * O + o) * ((size_t)G * K) + (size_t)(r % G) * K + d] = f2bf(W[i]);
}

// ===== gather NR relations per dst row, ILP-4 over the contiguous edge range =====
template<int D, int NR>
__global__ void gatherN_k(const ushort* __restrict__ xb, const int* __restrict__ slist,
                          const int* __restrict__ off, int r0,
                          ushort* __restrict__ agg, int N) {
  constexpr int V = D / 64;  // ushorts per lane
  const int lane = threadIdx.x & 63;
  const int d = (blockIdx.x * blockDim.x + threadIdx.x) >> 6;
  if (d >= N) return;
  int o[NR + 1];
#pragma unroll
  for (int j = 0; j <= NR; ++j) o[j] = off[d * NREL + r0 + j];
  const int bc = lane * V;
  float s[NR][V];
#pragma unroll
  for (int r = 0; r < NR; ++r)
#pragma unroll
    for (int v = 0; v < V; ++v) s[r][v] = 0.f;

  const int base = o[0], total = o[NR] - base;
  for (int i0 = 0; i0 < total; i0 += 4) {
    // issue up to 4 independent row loads (raw), then consume
    uint  raw2[4];
    uint2 raw4[4];
#pragma unroll
    for (int u = 0; u < 4; ++u) {
      if (i0 + u < total) {
        int e = slist[base + i0 + u];
        const ushort* xp = xb + (size_t)e * D + bc;
        if constexpr (V == 2) raw2[u] = *(const uint*)xp;
        else                  raw4[u] = *(const uint2*)xp;
      }
    }
#pragma unroll
    for (int u = 0; u < 4; ++u) {
      if (i0 + u < total) {
        int gj = base + i0 + u;
        float f[V];
        if constexpr (V == 2) {
          f[0] = bf2f((ushort)(raw2[u] & 0xffff));
          f[1] = bf2f((ushort)(raw2[u] >> 16));
        } else {
          f[0] = bf2f((ushort)(raw4[u].x & 0xffff));
          f[1] = bf2f((ushort)(raw4[u].x >> 16));
          f[2] = bf2f((ushort)(raw4[u].y & 0xffff));
          f[3] = bf2f((ushort)(raw4[u].y >> 16));
        }
#pragma unroll
        for (int r = 0; r < NR; ++r) {
          if (gj >= o[r] && gj < o[r + 1]) {
#pragma unroll
            for (int v = 0; v < V; ++v) s[r][v] += f[v];
          }
        }
      }
    }
  }

#pragma unroll
  for (int r = 0; r < NR; ++r) {
    int c = o[r + 1] - o[r];
    float w = 1.f / (float)(c > 1 ? c : 1);
    ushort* mp = agg + (size_t)d * (NR * D) + r * D + bc;
    if constexpr (V == 2) {
      ushort2 st; st.x = f2bf(s[r][0] * w); st.y = f2bf(s[r][1] * w);
      *(ushort2*)mp = st;
    } else {
      ushort4 st; st.x = f2bf(s[r][0] * w); st.y = f2bf(s[r][1] * w);
      st.z = f2bf(s[r][2] * w); st.w = f2bf(s[r][3] * w);
      *(ushort4*)mp = st;
    }
  }
}

// ======================= bf16 MFMA GEMM, 2-phase reg-staged pipeline =======================
// C (+)= A[M,K]@Bt^T [+bias][relu].  Bt is [O][K] row-major.
// 128x128 tile, 4 waves (2x2), wave = 64x64 via 4x4 frags of 16x16x32. BK=64, XOR-swizzled LDS.
template<bool CF32>
__global__ __launch_bounds__(256)
void mgemm_k(const ushort* __restrict__ A, int K, const ushort* __restrict__ Bt,
             const float* __restrict__ bias, void* __restrict__ Cv,
             int loadC, int relu, int M, int O) {
  __shared__ ushort Al[128 * 64];
  __shared__ ushort Bl[128 * 64];
  const int tid = threadIdx.x;
  const int lane = tid & 63;
  const int w = tid >> 6;
  const int wr = (w >> 1) * 64;
  const int wc = (w & 1) * 64;
  const int m0 = blockIdx.x * 128;
  const int n0 = blockIdx.y * 128;

  f32x4 acc[4][4];
#pragma unroll
  for (int i = 0; i < 4; ++i)
#pragma unroll
    for (int j = 0; j < 4; ++j) acc[i][j] = (f32x4){0.f, 0.f, 0.f, 0.f};

  const int srow = tid >> 3;   // 0..31
  const int schk = tid & 7;    // 0..7 (16B chunk within 128B row)

  uint4 ra[4], rb[4];          // staged next k-tile (issue-early / write-late)
  auto gload = [&](int k0) {
#pragma unroll
    for (int p = 0; p < 4; ++p) {
      int row = p * 32 + srow;
      int gm = m0 + row;
      ra[p] = make_uint4(0, 0, 0, 0);
      if (gm < M) ra[p] = *(const uint4*)(A + (size_t)gm * K + k0 + schk * 8);
      rb[p] = *(const uint4*)(Bt + (size_t)(n0 + row) * K + k0 + schk * 8);
    }
  };
  auto swrite = [&]() {
#pragma unroll
    for (int p = 0; p < 4; ++p) {
      int row = p * 32 + srow;
      *(uint4*)&Al[row * 64 + ((schk ^ (row & 7)) * 8)] = ra[p];
      *(uint4*)&Bl[row * 64 + ((schk ^ (row & 7)) * 8)] = rb[p];
    }
  };

  gload(0);
  const int nt = K >> 6;
  for (int t = 0; t < nt; ++t) {
    swrite();                    // implicit vmcnt wait on ra/rb
    __syncthreads();
    if (t + 1 < nt) gload((t + 1) << 6);   // in flight during compute
#pragma unroll
    for (int kk = 0; kk < 2; ++kk) {
      bf16x8 a_f[4], b_f[4];
      int slot = kk * 4 + (lane >> 4);
#pragma unroll
      for (int f = 0; f < 4; ++f) {
        int mr = wr + f * 16 + (lane & 15);
        a_f[f] = *(const bf16x8*)&Al[mr * 64 + ((slot ^ (mr & 7)) * 8)];
        int nc = wc + f * 16 + (lane & 15);
        b_f[f] = *(const bf16x8*)&Bl[nc * 64 + ((slot ^ (nc & 7)) * 8)];
      }
#pragma unroll
      for (int i = 0; i < 4; ++i)
#pragma unroll
        for (int j = 0; j < 4; ++j)
          acc[i][j] = __builtin_amdgcn_mfma_f32_16x16x32_bf16(a_f[i], b_f[j], acc[i][j], 0, 0, 0);
    }
    __syncthreads();
  }

  float bv[4];
#pragma unroll
  for (int j = 0; j < 4; ++j) bv[j] = bias ? bias[n0 + wc + j * 16 + (lane & 15)] : 0.f;
#pragma unroll
  for (int i = 0; i < 4; ++i) {
#pragma unroll
    for (int rg = 0; rg < 4; ++rg) {
      int row = m0 + wr + i * 16 + (lane >> 4) * 4 + rg;
      if (row < M) {
#pragma unroll
        for (int j = 0; j < 4; ++j) {
          int col = n0 + wc + j * 16 + (lane & 15);
          float v = acc[i][j][rg] + bv[j];
          if (CF32) {
            float* C = (float*)Cv + (size_t)row * O + col;
            if (loadC) v += *C;
            if (relu) v = fmaxf(v, 0.f);
            *C = v;
          } else {
            ushort* C = (ushort*)Cv + (size_t)row * O + col;
            if (loadC) v += bf2f(*C);
            if (relu) v = fmaxf(v, 0.f);
            *C = f2bf(v);
          }
        }
      }
    }
  }
}

extern "C" void kernel_launch(void* const* d_in, const int* in_sizes, int n_in,
                              void* d_out, int out_size, void* d_ws, size_t ws_size,
                              hipStream_t stream) {
  const float* x  = (const float*)d_in[0];
  const int* eidx = (const int*)d_in[1];
  const int* etyp = (const int*)d_in[2];
  const float* W1 = (const float*)d_in[3];
  const float* r1 = (const float*)d_in[4];
  const float* b1 = (const float*)d_in[5];
  const float* W2 = (const float*)d_in[6];
  const float* r2 = (const float*)d_in[7];
  const float* b2 = (const float*)d_in[8];
  const float* W3 = (const float*)d_in[9];
  const float* r3 = (const float*)d_in[10];
  const float* b3 = (const float*)d_in[11];
  float* out = (float*)d_out;

  const int N = in_sizes[0] / 128;  // 50000
  const int E = in_sizes[2];        // 800000
  const int* src = eidx;
  const int* dst = eidx + E;
  const int NSEG = N * NREL;
  const int NB = (NSEG + SCHUNK - 1) / SCHUNK;
  (void)n_in; (void)out_size;

  // workspace carve (175.36 MB == round-9 footprint, guard-proven to fit)
  auto al = [](size_t v) { return (v + 255) & ~(size_t)255; };
  char* p = (char*)d_ws;
  int* cnt    = (int*)p;    p += al((size_t)NSEG * 4);
  int* off    = (int*)p;    p += al((size_t)(NSEG + 1) * 4);
  int* thexc  = (int*)p;    p += al((size_t)NB * 256 * 4);
  int* bsum   = (int*)p;    p += al((size_t)NB * 4);
  int* slist  = (int*)p;    p += al((size_t)E * 4);
  ushort* xb  = (ushort*)p; p += al((size_t)N * 128 * 2);
  ushort* h1  = (ushort*)p; p += al((size_t)N * 256 * 2);
  ushort* h2  = (ushort*)p; p += al((size_t)N * 256 * 2);
  ushort* agg = (ushort*)p; p += al((size_t)N * 1024 * 2);   // [N][NR*D] = [N][1024]
  ushort* wt1 = (ushort*)p; p += al((size_t)NREL * 128 * 256 * 2);
  ushort* rt1 = (ushort*)p; p += al((size_t)128 * 256 * 2);
  ushort* wt2 = (ushort*)p; p += al((size_t)NREL * 256 * 256 * 2);
  ushort* rt2 = (ushort*)p; p += al((size_t)256 * 256 * 2);
  ushort* wt3 = (ushort*)p; p += al((size_t)NREL * 256 * 128 * 2);
  ushort* rt3 = (ushort*)p; p += al((size_t)256 * 128 * 2);
  size_t used = (size_t)(p - (char*)d_ws);
  if (used > ws_size) return;  // fail clean, not SIGABRT

  // Insurance (proven necessary in R12): identical initial ws state every call.
  hipMemsetAsync(d_ws, 0, used, stream);

  // ---- CSR over (dst,rel), built once per call ----
  hist_k<<<(E + 255) / 256, 256, 0, stream>>>(dst, etyp, cnt, E);
  scan1_k<<<NB, 256, 0, stream>>>(cnt, NSEG, thexc, bsum);
  scan2_k<<<1, 1, 0, stream>>>(bsum, NB, E, off, NSEG);
  scan3_k<<<NB, 256, 0, stream>>>(cnt, NSEG, thexc, bsum, off, cnt);
  fill2_k<<<(E + 255) / 256, 256, 0, stream>>>(src, dst, etyp, E, cnt, slist);

  // ---- conversions ----
  f2b_k<<<(N * 128 / 4 + 255) / 256, 256, 0, stream>>>(x, xb, N * 128 / 4);
  auto wconv = [&](const float* W, ushort* Wt, int R, int K, int O, int G) {
    size_t tot = (size_t)R * K * O;
    wt_k<<<(int)((tot + 255) / 256), 256, 0, stream>>>(W, Wt, R, K, O, G);
  };
  wconv(W1, wt1, NREL, 128, 256, 8);   // one group of 8 -> K=1024
  wconv(r1, rt1, 1, 128, 256, 1);
  wconv(W2, wt2, NREL, 256, 256, 4);   // two groups of 4 -> K=1024
  wconv(r2, rt2, 1, 256, 256, 1);
  wconv(W3, wt3, NREL, 256, 128, 4);
  wconv(r3, rt3, 1, 256, 128, 1);

  const int gblocks = (N * 64 + 255) / 256;

  // ---- one layer: root pass writes C(+bias); NP K=1024 relation passes RMW; relu on last ----
  auto layer = [&](const ushort* xin, int D, int NP, const ushort* Wt, const ushort* Rt,
                   const float* bias, void* Y, int O, bool relu, bool cf32) {
    dim3 g((N + 127) / 128, O / 128);
    if (cf32)
      mgemm_k<true><<<g, 256, 0, stream>>>(xin, D, Rt, bias, Y, 0, 0, N, O);
    else
      mgemm_k<false><<<g, 256, 0, stream>>>(xin, D, Rt, bias, Y, 0, 0, N, O);
    int NR = NREL / NP;  // 8 (D=128) or 4 (D=256)
    for (int pass = 0; pass < NP; ++pass) {
      if (D == 128)
        gatherN_k<128, 8><<<gblocks, 256, 0, stream>>>(xin, slist, off, pass * 8, agg, N);
      else
        gatherN_k<256, 4><<<gblocks, 256, 0, stream>>>(xin, slist, off, pass * 4, agg, N);
      const ushort* Bt = Wt + (size_t)pass * O * (NR * D);
      int rl = (relu && pass == NP - 1) ? 1 : 0;
      if (cf32)
        mgemm_k<true><<<g, 256, 0, stream>>>(agg, NR * D, Bt, nullptr, Y, 1, rl, N, O);
      else
        mgemm_k<false><<<g, 256, 0, stream>>>(agg, NR * D, Bt, nullptr, Y, 1, rl, N, O);
    }
  };

  layer(xb, 128, 1, wt1, rt1, b1, h1, 256, true,  false);
  layer(h1, 256, 2, wt2, rt2, b2, h2, 256, true,  false);
  layer(h2, 256, 2, wt3, rt3, b3, out, 128, false, true);
}